// Round 6
// baseline (259.293 us; speedup 1.0000x reference)
//
#include <hip/hip_runtime.h>
#include <hip/hip_bf16.h>

// GPT-2 attention: B=2, S=2048, D=1024, H=16, HS=64
// cvt(x)->bf16 ; transpose weights -> [N][K] bf16 ; GEMM1 (QKV proj, single-buffer,
// Q scaled by 0.125*log2e, V via LDS-transpose coalesced epilogue) ; flash attention
// (128-row q-tiles, 8 waves, KVBLK=128, 17 balanced rounds/CU, swizzled LDS, exp2
// softmax, defer-max) ; GEMM2 (single-buffer, +bias, fp32 out).

#define Bb 2
#define Ss 2048
#define Dd 1024
#define Hh 16
#define HSs 64

typedef __bf16 bf16x8 __attribute__((ext_vector_type(8)));
typedef float  f32x4  __attribute__((ext_vector_type(4)));

__device__ __forceinline__ unsigned short f2bf(float f) {
  unsigned int u = __float_as_uint(f);
  unsigned int lsb = (u >> 16) & 1u;
  u += 0x7fffu + lsb;               // round-to-nearest-even (finite values)
  return (unsigned short)(u >> 16);
}

__device__ __forceinline__ void async16(const unsigned short* g, unsigned short* l) {
  __builtin_amdgcn_global_load_lds(
      (const __attribute__((address_space(1))) unsigned int*)g,
      (__attribute__((address_space(3))) unsigned int*)l,
      16, 0, 0);
}

// ---------------------------------------------------------------- cvt x -> bf16
__global__ __launch_bounds__(256) void k_cvt_bf16(const float* __restrict__ in,
                                                  unsigned short* __restrict__ out,
                                                  int n) {
  int i = (blockIdx.x * 256 + threadIdx.x) * 4;
  int stride = gridDim.x * 256 * 4;
  for (; i < n; i += stride) {
    float4 v = *reinterpret_cast<const float4*>(in + i);
    ushort4 o;
    o.x = f2bf(v.x); o.y = f2bf(v.y); o.z = f2bf(v.z); o.w = f2bf(v.w);
    *reinterpret_cast<ushort4*>(out + i) = o;
  }
}

// ------------------------------------------------- transpose f32 [R][C] -> bf16 [C][R]
__global__ __launch_bounds__(256) void k_transpose_bf16(const float* __restrict__ in,
                                                        unsigned short* __restrict__ out,
                                                        int R, int C) {
  __shared__ float t[32][33];
  int c0 = blockIdx.x * 32, r0 = blockIdx.y * 32;
  int tx = threadIdx.x, ty = threadIdx.y;  // block (32,8)
  #pragma unroll
  for (int i = 0; i < 32; i += 8)
    t[ty + i][tx] = in[(size_t)(r0 + ty + i) * C + (c0 + tx)];
  __syncthreads();
  #pragma unroll
  for (int i = 0; i < 32; i += 8)
    out[(size_t)(c0 + ty + i) * R + (r0 + tx)] = f2bf(t[tx][ty + i]);
}

// ---------------------------------------------------------------- GEMM1: QKV proj
// single-buffer 32KB; V blocks (n0>=2048) use LDS-transpose epilogue for coalesced Vt writes
__global__ __launch_bounds__(256) void k_gemm_qkv(const unsigned short* __restrict__ A,
                                                  const unsigned short* __restrict__ Bt,
                                                  const float* __restrict__ bias,
                                                  unsigned short* __restrict__ Qg,
                                                  unsigned short* __restrict__ Kg,
                                                  unsigned short* __restrict__ Vt) {
  __shared__ unsigned short S[2][128 * 64];   // S[0]=As, S[1]=Bs; reused as 128x128 Ts
  const int K = 1024;
  int bid = blockIdx.x;
  int swz = (bid % 8) * 96 + bid / 8;         // XCD-contiguous
  int tm = swz / 24, tn = swz % 24;
  int m0 = tm * 128, n0 = tn * 128;
  int tid = threadIdx.x;
  int w = tid >> 6, l = tid & 63;
  int lr = l & 15, lg = l >> 4;
  int wm = (w >> 1) * 64, wn = (w & 1) * 64;
  int srow = l >> 3, scol = (l & 7) * 8;

  f32x4 acc[4][4];
  #pragma unroll
  for (int i = 0; i < 4; ++i)
    #pragma unroll
    for (int j = 0; j < 4; ++j)
      acc[i][j] = (f32x4){0.f, 0.f, 0.f, 0.f};

  for (int k0 = 0; k0 < K; k0 += 64) {
    #pragma unroll
    for (int c = 0; c < 4; ++c) {
      int chunk = w * 4 + c;
      int row = chunk * 8 + srow;
      async16(&A[(size_t)(m0 + row) * K + k0 + scol], &S[0][chunk * 512]);
      async16(&Bt[(size_t)(n0 + row) * K + k0 + scol], &S[1][chunk * 512]);
    }
    __syncthreads();
    #pragma unroll
    for (int kk = 0; kk < 64; kk += 32) {
      bf16x8 af[4], bfr[4];
      #pragma unroll
      for (int mf = 0; mf < 4; ++mf)
        af[mf] = *reinterpret_cast<const bf16x8*>(&S[0][(wm + mf * 16 + lr) * 64 + kk + lg * 8]);
      #pragma unroll
      for (int nf = 0; nf < 4; ++nf)
        bfr[nf] = *reinterpret_cast<const bf16x8*>(&S[1][(wn + nf * 16 + lr) * 64 + kk + lg * 8]);
      #pragma unroll
      for (int mf = 0; mf < 4; ++mf)
        #pragma unroll
        for (int nf = 0; nf < 4; ++nf)
          acc[mf][nf] = __builtin_amdgcn_mfma_f32_16x16x32_bf16(af[mf], bfr[nf], acc[mf][nf], 0, 0, 0);
    }
    __syncthreads();
  }

  if (n0 < 2048) {
    // Q / K scatter (t uniform per block since n-range of 128 fits one 1024 segment)
    #pragma unroll
    for (int mf = 0; mf < 4; ++mf) {
      #pragma unroll
      for (int nf = 0; nf < 4; ++nf) {
        int n = n0 + wn + nf * 16 + lr;
        int t = n >> 10, r = n & 1023;
        int h = r >> 6, cc = r & 63;
        float bv = bias[n];
        #pragma unroll
        for (int j = 0; j < 4; ++j) {
          int m = m0 + wm + mf * 16 + lg * 4 + j;
          int b = m >> 11, s = m & 2047;
          size_t idx = ((size_t)(b * Hh + h) * Ss + s) * HSs + cc;
          float v = acc[mf][nf][j] + bv;
          // Q pre-scaled by (1/8)*log2(e): attention softmax runs in exp2 domain
          if (t == 0) Qg[idx] = f2bf(v * 0.1803368801111244f);
          else        Kg[idx] = f2bf(v);
        }
      }
    }
  } else {
    // V: transpose 128x128 tile in LDS, write coalesced rows along s
    unsigned short* Ts = &S[0][0];            // [128 n][128 m], XOR-swizzled
    #pragma unroll
    for (int mf = 0; mf < 4; ++mf)
      #pragma unroll
      for (int nf = 0; nf < 4; ++nf) {
        int nl = wn + nf * 16 + lr;
        float bv = bias[n0 + nl];
        #pragma unroll
        for (int j = 0; j < 4; ++j) {
          int ml = wm + mf * 16 + lg * 4 + j;
          Ts[nl * 128 + (ml ^ ((nl & 7) << 3))] = f2bf(acc[mf][nf][j] + bv);
        }
      }
    __syncthreads();
    int nl = tid >> 1, mh = (tid & 1) * 64;
    int n = n0 + nl;
    int h = (n & 1023) >> 6, cc = n & 63;
    int bb = m0 >> 11, s0 = m0 & 2047;
    unsigned short* dst = &Vt[((size_t)(bb * Hh + h) * HSs + cc) * Ss + s0];
    #pragma unroll
    for (int i = 0; i < 8; ++i) {
      int m = mh + i * 8;
      bf16x8 v = *reinterpret_cast<const bf16x8*>(&Ts[nl * 128 + (m ^ ((nl & 7) << 3))]);
      *reinterpret_cast<bf16x8*>(&dst[m]) = v;
    }
  }
}

// ---------------------------------------------------------------- flash attention
// grid 512: bid = c*256 + bh*8 + p. qt = c ? 15-p : p. 512 threads = 8 waves, each 16 q-rows
// (128-row q-tile). KVBLK=128, single-buffer, 2 barriers/round. Per-CU (stride-256 pair):
// (p+1)+(16-p) = 17 rounds exactly, same bh. LDS 64KB -> 2 blocks/CU.
__global__ __launch_bounds__(512, 4) void k_attn(const unsigned short* __restrict__ Qg,
                                                 const unsigned short* __restrict__ Kg,
                                                 const unsigned short* __restrict__ Vt,
                                                 unsigned short* __restrict__ Ob) {
  __shared__ unsigned short Ks[128 * 64];     // [s][c] 16KB
  __shared__ unsigned short Vs[64 * 128];     // [c][s] 16KB
  __shared__ unsigned short Ps[8][16 * 128];  // per-wave P, 32KB

  int bid = blockIdx.x;
  int c = bid >> 8, bh = (bid >> 3) & 31, p = bid & 7;
  int qt = c ? (15 - p) : p;
  int b = bh >> 4, h = bh & 15;
  int qs0 = qt * 128;

  int tid = threadIdx.x;
  int w = tid >> 6, l = tid & 63;
  int lr = l & 15, lg = l >> 4;
  int qw = qs0 + w * 16;
  int srow = l >> 3, scolK = (l & 7) * 8;     // K chunk: 8 rows x 64 cols
  int rrV = l >> 4, colV = (l & 15) * 8;      // V chunk: 4 rows x 128 cols

  // Q fragments: rows qw+lr, cols kx*32 + lg*8
  bf16x8 qf[2];
  #pragma unroll
  for (int kx = 0; kx < 2; ++kx)
    qf[kx] = *reinterpret_cast<const bf16x8*>(
        &Qg[((size_t)bh * Ss + qw + lr) * HSs + kx * 32 + lg * 8]);

  f32x4 oacc[4];
  #pragma unroll
  for (int nf = 0; nf < 4; ++nf) oacc[nf] = (f32x4){0.f, 0.f, 0.f, 0.f};
  float mrun[4], lrun[4];
  #pragma unroll
  for (int j = 0; j < 4; ++j) { mrun[j] = -1e30f; lrun[j] = 0.f; }

  int ntiles = qt + 1;
  for (int t = 0; t < ntiles; ++t) {
    // stage tile t (16 chunks of 1KB each for K and V; wave w does chunks w*2, w*2+1)
    #pragma unroll
    for (int cc = 0; cc < 2; ++cc) {
      int ch = w * 2 + cc;
      int rowK = ch * 8 + srow;
      int swK = scolK ^ ((srow & 7) << 3);
      async16(&Kg[((size_t)bh * Ss + t * 128 + rowK) * HSs + swK], &Ks[ch * 512]);
      int rowV = ch * 4 + rrV;
      int swV = colV ^ ((rowV & 7) << 3);
      async16(&Vt[((size_t)bh * HSs + rowV) * Ss + t * 128 + swV], &Vs[ch * 512]);
    }
    __syncthreads();    // drains global_load_lds (vmcnt 0) + all waves ready

    // QK^T: 128 cols (8 n-frags), scores in log2 domain via Q pre-scale
    f32x4 sacc[8];
    #pragma unroll
    for (int nf = 0; nf < 8; ++nf) sacc[nf] = (f32x4){0.f, 0.f, 0.f, 0.f};
    #pragma unroll
    for (int kx = 0; kx < 2; ++kx) {
      #pragma unroll
      for (int nf = 0; nf < 8; ++nf) {
        int rk = nf * 16 + lr;
        bf16x8 kf = *reinterpret_cast<const bf16x8*>(
            &Ks[rk * 64 + ((kx * 32 + lg * 8) ^ ((rk & 7) << 3))]);
        sacc[nf] = __builtin_amdgcn_mfma_f32_16x16x32_bf16(qf[kx], kf, sacc[nf], 0, 0, 0);
      }
    }

    if (t == qt) {                            // diagonal tile: causal mask
      #pragma unroll
      for (int nf = 0; nf < 8; ++nf) {
        int kcol = qs0 + nf * 16 + lr;
        #pragma unroll
        for (int j = 0; j < 4; ++j) {
          int qg2 = qw + lg * 4 + j;
          if (kcol > qg2) sacc[nf][j] = -1e30f;
        }
      }
    }

    // online softmax, exp2 domain (row = lg*4+j, cols = nf*16+lr over 128)
    float rmax[4];
    #pragma unroll
    for (int j = 0; j < 4; ++j) {
      float rm = fmaxf(fmaxf(fmaxf(sacc[0][j], sacc[1][j]), fmaxf(sacc[2][j], sacc[3][j])),
                       fmaxf(fmaxf(sacc[4][j], sacc[5][j]), fmaxf(sacc[6][j], sacc[7][j])));
      #pragma unroll
      for (int d = 1; d < 16; d <<= 1)
        rm = fmaxf(rm, __shfl_xor(rm, d));
      rmax[j] = rm;
    }
    bool need = (rmax[0] > mrun[0] + 8.f) | (rmax[1] > mrun[1] + 8.f) |
                (rmax[2] > mrun[2] + 8.f) | (rmax[3] > mrun[3] + 8.f);
    if (__any(need)) {
      #pragma unroll
      for (int j = 0; j < 4; ++j) {
        float mnew = fmaxf(mrun[j], rmax[j]);
        float cf = exp2f(mrun[j] - mnew);
        mrun[j] = mnew;
        lrun[j] *= cf;
        #pragma unroll
        for (int nf = 0; nf < 4; ++nf)
          oacc[nf][j] *= cf;
      }
    }
    #pragma unroll
    for (int j = 0; j < 4; ++j) {
      float psum = 0.f;
      #pragma unroll
      for (int nf = 0; nf < 8; ++nf) {
        float pv = exp2f(sacc[nf][j] - mrun[j]);
        sacc[nf][j] = pv;
        psum += pv;
      }
      #pragma unroll
      for (int d = 1; d < 16; d <<= 1)
        psum += __shfl_xor(psum, d);
      lrun[j] += psum;
    }

    // P -> LDS (per-wave [16][128], XOR-swizzled)
    #pragma unroll
    for (int nf = 0; nf < 8; ++nf)
      #pragma unroll
      for (int j = 0; j < 4; ++j) {
        int prow = lg * 4 + j;
        Ps[w][prow * 128 + ((nf * 16 + lr) ^ ((prow & 7) << 3))] = f2bf(sacc[nf][j]);
      }

    // PV: K-dim = 128 (4 kx slabs)
    #pragma unroll
    for (int kx = 0; kx < 4; ++kx) {
      bf16x8 pf = *reinterpret_cast<const bf16x8*>(
          &Ps[w][lr * 128 + ((kx * 32 + lg * 8) ^ ((lr & 7) << 3))]);
      #pragma unroll
      for (int nf = 0; nf < 4; ++nf) {
        int rv = nf * 16 + lr;
        bf16x8 vf = *reinterpret_cast<const bf16x8*>(
            &Vs[rv * 128 + ((kx * 32 + lg * 8) ^ ((rv & 7) << 3))]);
        oacc[nf] = __builtin_amdgcn_mfma_f32_16x16x32_bf16(pf, vf, oacc[nf], 0, 0, 0);
      }
    }
    __syncthreads();    // all waves done reading Ks/Vs before next-tile stage
  }

  #pragma unroll
  for (int j = 0; j < 4; ++j) {
    float rinv = 1.0f / lrun[j];
    int s = qw + lg * 4 + j;
    #pragma unroll
    for (int nf = 0; nf < 4; ++nf) {
      int cc = nf * 16 + lr;
      Ob[((size_t)(b * Ss + s)) * Dd + h * HSs + cc] = f2bf(oacc[nf][j] * rinv);
    }
  }
}

// ---------------------------------------------------------------- GEMM2: out proj (single-buffer)
__global__ __launch_bounds__(256) void k_gemm_out(const unsigned short* __restrict__ A,
                                                  const unsigned short* __restrict__ Bt,
                                                  const float* __restrict__ bias,
                                                  float* __restrict__ Out) {
  __shared__ unsigned short As[128 * 64];
  __shared__ unsigned short Bs[128 * 64];
  const int K = 1024;
  int bid = blockIdx.x;
  int swz = (bid % 8) * 32 + bid / 8;       // XCD-contiguous
  int tm = swz / 8, tn = swz % 8;
  int m0 = tm * 128, n0 = tn * 128;
  int tid = threadIdx.x;
  int w = tid >> 6, l = tid & 63;
  int lr = l & 15, lg = l >> 4;
  int wm = (w >> 1) * 64, wn = (w & 1) * 64;
  int srow = l >> 3, scol = (l & 7) * 8;

  f32x4 acc[4][4];
  #pragma unroll
  for (int i = 0; i < 4; ++i)
    #pragma unroll
    for (int j = 0; j < 4; ++j)
      acc[i][j] = (f32x4){0.f, 0.f, 0.f, 0.f};

  for (int k0 = 0; k0 < K; k0 += 64) {
    #pragma unroll
    for (int c = 0; c < 4; ++c) {
      int chunk = w * 4 + c;
      int row = chunk * 8 + srow;
      async16(&A[(size_t)(m0 + row) * K + k0 + scol], &As[chunk * 512]);
      async16(&Bt[(size_t)(n0 + row) * K + k0 + scol], &Bs[chunk * 512]);
    }
    __syncthreads();
    #pragma unroll
    for (int kk = 0; kk < 64; kk += 32) {
      bf16x8 af[4], bfr[4];
      #pragma unroll
      for (int mf = 0; mf < 4; ++mf)
        af[mf] = *reinterpret_cast<const bf16x8*>(&As[(wm + mf * 16 + lr) * 64 + kk + lg * 8]);
      #pragma unroll
      for (int nf = 0; nf < 4; ++nf)
        bfr[nf] = *reinterpret_cast<const bf16x8*>(&Bs[(wn + nf * 16 + lr) * 64 + kk + lg * 8]);
      #pragma unroll
      for (int mf = 0; mf < 4; ++mf)
        #pragma unroll
        for (int nf = 0; nf < 4; ++nf)
          acc[mf][nf] = __builtin_amdgcn_mfma_f32_16x16x32_bf16(af[mf], bfr[nf], acc[mf][nf], 0, 0, 0);
    }
    __syncthreads();
  }

  #pragma unroll
  for (int mf = 0; mf < 4; ++mf)
    #pragma unroll
    for (int nf = 0; nf < 4; ++nf) {
      int n = n0 + wn + nf * 16 + lr;
      float bv = bias[n];
      #pragma unroll
      for (int j = 0; j < 4; ++j) {
        int m = m0 + wm + mf * 16 + lg * 4 + j;
        Out[(size_t)m * 1024 + n] = acc[mf][nf][j] + bv;
      }
    }
}

// ---------------------------------------------------------------- launch
extern "C" void kernel_launch(void* const* d_in, const int* in_sizes, int n_in,
                              void* d_out, int out_size, void* d_ws, size_t ws_size,
                              hipStream_t stream) {
  (void)in_sizes; (void)n_in; (void)out_size; (void)ws_size;
  const float* x      = (const float*)d_in[0];
  const float* w_qkv  = (const float*)d_in[2];
  const float* b_qkv  = (const float*)d_in[3];
  const float* w_proj = (const float*)d_in[4];
  const float* b_proj = (const float*)d_in[5];
  float* out = (float*)d_out;

  char* ws = (char*)d_ws;
  unsigned short* xb    = (unsigned short*)(ws);              //  8 MB [4096][1024]
  unsigned short* wqkvT = (unsigned short*)(ws + 8388608);    //  6 MB [3072][1024]
  unsigned short* wpT   = (unsigned short*)(ws + 14680064);   //  2 MB [1024][1024]
  unsigned short* Qg    = (unsigned short*)(ws + 16777216);   //  8 MB [32][2048][64]
  unsigned short* Kg    = (unsigned short*)(ws + 25165824);   //  8 MB [32][2048][64]
  unsigned short* Vt    = (unsigned short*)(ws + 33554432);   //  8 MB [32][64][2048]
  unsigned short* attnb = (unsigned short*)(ws + 41943040);   //  8 MB [4096][1024]

  k_cvt_bf16<<<dim3(2048), dim3(256), 0, stream>>>(x, xb, Bb * Ss * Dd);
  k_transpose_bf16<<<dim3(96, 32), dim3(32, 8), 0, stream>>>(w_qkv, wqkvT, 1024, 3072);
  k_transpose_bf16<<<dim3(32, 32), dim3(32, 8), 0, stream>>>(w_proj, wpT, 1024, 1024);
  k_gemm_qkv<<<dim3(32 * 24), dim3(256), 0, stream>>>(xb, wqkvT, b_qkv, Qg, Kg, Vt);
  k_attn<<<dim3(512), dim3(512), 0, stream>>>(Qg, Kg, Vt, attnb);
  k_gemm_out<<<dim3(32 * 8), dim3(256), 0, stream>>>(attnb, wpT, b_proj, out);
}

// Round 7
// 245.338 us; speedup vs baseline: 1.0569x; 1.0569x over previous
//
#include <hip/hip_runtime.h>
#include <hip/hip_bf16.h>

// GPT-2 attention: B=2, S=2048, D=1024, H=16, HS=64
// cvt(x)->bf16 ; transpose weights -> [N][K] bf16 ; GEMM1 (QKV proj, Q scaled by
// 0.125*log2e, V via LDS-transpose coalesced epilogue) ; flash attention (dual
// sequential q-tiles per block = 33 balanced rounds, barrier-at-top prefetch,
// bh-pinned XCD, swizzled LDS, exp2 softmax, defer-max) ; GEMM2 (+bias, fp32).

#define Bb 2
#define Ss 2048
#define Dd 1024
#define Hh 16
#define HSs 64

typedef __bf16 bf16x8 __attribute__((ext_vector_type(8)));
typedef float  f32x4  __attribute__((ext_vector_type(4)));

__device__ __forceinline__ unsigned short f2bf(float f) {
  unsigned int u = __float_as_uint(f);
  unsigned int lsb = (u >> 16) & 1u;
  u += 0x7fffu + lsb;               // round-to-nearest-even (finite values)
  return (unsigned short)(u >> 16);
}

__device__ __forceinline__ void async16(const unsigned short* g, unsigned short* l) {
  __builtin_amdgcn_global_load_lds(
      (const __attribute__((address_space(1))) unsigned int*)g,
      (__attribute__((address_space(3))) unsigned int*)l,
      16, 0, 0);
}

// ---------------------------------------------------------------- cvt x -> bf16
__global__ __launch_bounds__(256) void k_cvt_bf16(const float* __restrict__ in,
                                                  unsigned short* __restrict__ out,
                                                  int n) {
  int i = (blockIdx.x * 256 + threadIdx.x) * 4;
  int stride = gridDim.x * 256 * 4;
  for (; i < n; i += stride) {
    float4 v = *reinterpret_cast<const float4*>(in + i);
    ushort4 o;
    o.x = f2bf(v.x); o.y = f2bf(v.y); o.z = f2bf(v.z); o.w = f2bf(v.w);
    *reinterpret_cast<ushort4*>(out + i) = o;
  }
}

// ------------------------------------------------- transpose f32 [R][C] -> bf16 [C][R]
__global__ __launch_bounds__(256) void k_transpose_bf16(const float* __restrict__ in,
                                                        unsigned short* __restrict__ out,
                                                        int R, int C) {
  __shared__ float t[32][33];
  int c0 = blockIdx.x * 32, r0 = blockIdx.y * 32;
  int tx = threadIdx.x, ty = threadIdx.y;  // block (32,8)
  #pragma unroll
  for (int i = 0; i < 32; i += 8)
    t[ty + i][tx] = in[(size_t)(r0 + ty + i) * C + (c0 + tx)];
  __syncthreads();
  #pragma unroll
  for (int i = 0; i < 32; i += 8)
    out[(size_t)(c0 + ty + i) * R + (r0 + tx)] = f2bf(t[tx][ty + i]);
}

// ---------------------------------------------------------------- GEMM1: QKV proj
// single-buffer 32KB; V blocks (n0>=2048) use LDS-transpose epilogue for coalesced Vt writes
__global__ __launch_bounds__(256) void k_gemm_qkv(const unsigned short* __restrict__ A,
                                                  const unsigned short* __restrict__ Bt,
                                                  const float* __restrict__ bias,
                                                  unsigned short* __restrict__ Qg,
                                                  unsigned short* __restrict__ Kg,
                                                  unsigned short* __restrict__ Vt) {
  __shared__ unsigned short S[2][128 * 64];   // S[0]=As, S[1]=Bs; reused as 128x128 Ts
  const int K = 1024;
  int bid = blockIdx.x;
  int swz = (bid % 8) * 96 + bid / 8;         // XCD-contiguous
  int tm = swz / 24, tn = swz % 24;
  int m0 = tm * 128, n0 = tn * 128;
  int tid = threadIdx.x;
  int w = tid >> 6, l = tid & 63;
  int lr = l & 15, lg = l >> 4;
  int wm = (w >> 1) * 64, wn = (w & 1) * 64;
  int srow = l >> 3, scol = (l & 7) * 8;

  f32x4 acc[4][4];
  #pragma unroll
  for (int i = 0; i < 4; ++i)
    #pragma unroll
    for (int j = 0; j < 4; ++j)
      acc[i][j] = (f32x4){0.f, 0.f, 0.f, 0.f};

  for (int k0 = 0; k0 < K; k0 += 64) {
    #pragma unroll
    for (int c = 0; c < 4; ++c) {
      int chunk = w * 4 + c;
      int row = chunk * 8 + srow;
      async16(&A[(size_t)(m0 + row) * K + k0 + scol], &S[0][chunk * 512]);
      async16(&Bt[(size_t)(n0 + row) * K + k0 + scol], &S[1][chunk * 512]);
    }
    __syncthreads();
    #pragma unroll
    for (int kk = 0; kk < 64; kk += 32) {
      bf16x8 af[4], bfr[4];
      #pragma unroll
      for (int mf = 0; mf < 4; ++mf)
        af[mf] = *reinterpret_cast<const bf16x8*>(&S[0][(wm + mf * 16 + lr) * 64 + kk + lg * 8]);
      #pragma unroll
      for (int nf = 0; nf < 4; ++nf)
        bfr[nf] = *reinterpret_cast<const bf16x8*>(&S[1][(wn + nf * 16 + lr) * 64 + kk + lg * 8]);
      #pragma unroll
      for (int mf = 0; mf < 4; ++mf)
        #pragma unroll
        for (int nf = 0; nf < 4; ++nf)
          acc[mf][nf] = __builtin_amdgcn_mfma_f32_16x16x32_bf16(af[mf], bfr[nf], acc[mf][nf], 0, 0, 0);
    }
    __syncthreads();
  }

  if (n0 < 2048) {
    #pragma unroll
    for (int mf = 0; mf < 4; ++mf) {
      #pragma unroll
      for (int nf = 0; nf < 4; ++nf) {
        int n = n0 + wn + nf * 16 + lr;
        int t = n >> 10, r = n & 1023;
        int h = r >> 6, cc = r & 63;
        float bv = bias[n];
        #pragma unroll
        for (int j = 0; j < 4; ++j) {
          int m = m0 + wm + mf * 16 + lg * 4 + j;
          int b = m >> 11, s = m & 2047;
          size_t idx = ((size_t)(b * Hh + h) * Ss + s) * HSs + cc;
          float v = acc[mf][nf][j] + bv;
          // Q pre-scaled by (1/8)*log2(e): attention softmax runs in exp2 domain
          if (t == 0) Qg[idx] = f2bf(v * 0.1803368801111244f);
          else        Kg[idx] = f2bf(v);
        }
      }
    }
  } else {
    // V: transpose 128x128 tile in LDS, write coalesced rows along s
    unsigned short* Ts = &S[0][0];            // [128 n][128 m], XOR-swizzled
    #pragma unroll
    for (int mf = 0; mf < 4; ++mf)
      #pragma unroll
      for (int nf = 0; nf < 4; ++nf) {
        int nl = wn + nf * 16 + lr;
        float bv = bias[n0 + nl];
        #pragma unroll
        for (int j = 0; j < 4; ++j) {
          int ml = wm + mf * 16 + lg * 4 + j;
          Ts[nl * 128 + (ml ^ ((nl & 7) << 3))] = f2bf(acc[mf][nf][j] + bv);
        }
      }
    __syncthreads();
    int nl = tid >> 1, mh = (tid & 1) * 64;
    int n = n0 + nl;
    int h = (n & 1023) >> 6, cc = n & 63;
    int bb = m0 >> 11, s0 = m0 & 2047;
    unsigned short* dst = &Vt[((size_t)(bb * Hh + h) * HSs + cc) * Ss + s0];
    #pragma unroll
    for (int i = 0; i < 8; ++i) {
      int m = mh + i * 8;
      bf16x8 v = *reinterpret_cast<const bf16x8*>(&Ts[nl * 128 + (m ^ ((nl & 7) << 3))]);
      *reinterpret_cast<bf16x8*>(&dst[m]) = v;
    }
  }
}

// ---------------------------------------------------------------- flash attention
// grid 512: bid = q*32 + bh (bh in low bits -> XCD = bh&7 pinned, K/V L2-resident).
// Block = 4 waves x 16 q-rows (64-row q-tile), processes qtA=q then qtB=31-q
// SEQUENTIALLY -> exactly 33 rounds per block, all waves active every round.
// KVBLK=64 double-buffered; barrier at TOP of round so prefetch spans compute.
__global__ __launch_bounds__(256, 4) void k_attn(const unsigned short* __restrict__ Qg,
                                                 const unsigned short* __restrict__ Kg,
                                                 const unsigned short* __restrict__ Vt,
                                                 unsigned short* __restrict__ Ob) {
  __shared__ unsigned short Ks[2][64 * 64];   // 16 KB
  __shared__ unsigned short Vs[2][64 * 64];   // 16 KB
  __shared__ unsigned short Ps[4][16 * 64];   //  8 KB

  int bid = blockIdx.x;
  int q = bid >> 5, bh = bid & 31;
  int b = bh >> 4, h = bh & 15;
  int qtA = q, qtB = 31 - q;
  int ntA = qtA + 1;                          // rounds in phase A; total = 33

  int tid = threadIdx.x;
  int w = tid >> 6, l = tid & 63;
  int lr = l & 15, lg = l >> 4;
  int srow = l >> 3, scol = (l & 7) * 8;
  int swcol = scol ^ (srow << 3);             // pre-swizzled global source column

  const size_t kbase = (size_t)bh * Ss;       // rows of Kg
  const size_t vbase = (size_t)bh * HSs;      // rows of Vt

  // ---- per-phase state
  int qt = qtA, qs0 = qtA * 64, qw = qs0 + w * 16;
  bf16x8 qf[2];
  #pragma unroll
  for (int kx = 0; kx < 2; ++kx)
    qf[kx] = *reinterpret_cast<const bf16x8*>(
        &Qg[(kbase + qw + lr) * HSs + kx * 32 + lg * 8]);

  f32x4 oacc[4];
  #pragma unroll
  for (int nf = 0; nf < 4; ++nf) oacc[nf] = (f32x4){0.f, 0.f, 0.f, 0.f};
  float mrun[4], lrun[4];
  #pragma unroll
  for (int j = 0; j < 4; ++j) { mrun[j] = -1e30f; lrun[j] = 0.f; }

  // stage KV tile `tile` into buffer `buf` (wave w loads chunks 2w,2w+1 of K and V)
  auto stage = [&](int tile, int buf) {
    #pragma unroll
    for (int cch = 0; cch < 2; ++cch) {
      int rr = w * 16 + cch * 8 + srow;
      async16(&Kg[(kbase + tile * 64 + rr) * HSs + swcol], &Ks[buf][(w * 2 + cch) * 512]);
      async16(&Vt[(vbase + rr) * Ss + tile * 64 + swcol], &Vs[buf][(w * 2 + cch) * 512]);
    }
  };

  auto writeO = [&]() {
    #pragma unroll
    for (int j = 0; j < 4; ++j) {
      float rinv = 1.0f / lrun[j];
      int s = qw + lg * 4 + j;
      #pragma unroll
      for (int nf = 0; nf < 4; ++nf) {
        int cc = nf * 16 + lr;
        Ob[((size_t)(b * Ss + s)) * Dd + h * HSs + cc] = f2bf(oacc[nf][j] * rinv);
      }
    }
  };

  stage(0, 0);                                // prologue: phase-A tile 0

  for (int g = 0; g < 33; ++g) {
    __syncthreads();          // drains PREVIOUS prefetch (latency was hidden under compute)

    if (g + 1 < 33) {                         // prefetch for round g+1 (spans this compute)
      int nt = g + 1;
      int tile = (nt < ntA) ? nt : (nt - ntA);
      stage(tile, (g + 1) & 1);
    }

    if (g == ntA) {                           // phase switch A -> B (registers only)
      writeO();
      qt = qtB; qs0 = qtB * 64; qw = qs0 + w * 16;
      #pragma unroll
      for (int kx = 0; kx < 2; ++kx)
        qf[kx] = *reinterpret_cast<const bf16x8*>(
            &Qg[(kbase + qw + lr) * HSs + kx * 32 + lg * 8]);
      #pragma unroll
      for (int nf = 0; nf < 4; ++nf) oacc[nf] = (f32x4){0.f, 0.f, 0.f, 0.f};
      #pragma unroll
      for (int j = 0; j < 4; ++j) { mrun[j] = -1e30f; lrun[j] = 0.f; }
    }

    int t = (g < ntA) ? g : g - ntA;          // tile index within current phase
    int cur = g & 1;

    // QK^T (scores in log2 domain via Q pre-scale)
    f32x4 sacc[4];
    #pragma unroll
    for (int nf = 0; nf < 4; ++nf) sacc[nf] = (f32x4){0.f, 0.f, 0.f, 0.f};
    #pragma unroll
    for (int kx = 0; kx < 2; ++kx) {
      bf16x8 kf[4];
      #pragma unroll
      for (int nf = 0; nf < 4; ++nf)
        kf[nf] = *reinterpret_cast<const bf16x8*>(
            &Ks[cur][(nf * 16 + lr) * 64 + ((kx * 32 + lg * 8) ^ ((lr & 7) << 3))]);
      #pragma unroll
      for (int nf = 0; nf < 4; ++nf)
        sacc[nf] = __builtin_amdgcn_mfma_f32_16x16x32_bf16(qf[kx], kf[nf], sacc[nf], 0, 0, 0);
    }

    if (t == qt) {                            // diagonal tile: causal mask
      #pragma unroll
      for (int nf = 0; nf < 4; ++nf) {
        int kcol = t * 64 + nf * 16 + lr;
        #pragma unroll
        for (int j = 0; j < 4; ++j) {
          int qg2 = qw + lg * 4 + j;
          if (kcol > qg2) sacc[nf][j] = -1e30f;
        }
      }
    }

    // online softmax, exp2 domain (row = lg*4+j, cols = nf*16+lr)
    float rmax[4];
    #pragma unroll
    for (int j = 0; j < 4; ++j) {
      float rm = fmaxf(fmaxf(sacc[0][j], sacc[1][j]), fmaxf(sacc[2][j], sacc[3][j]));
      #pragma unroll
      for (int d = 1; d < 16; d <<= 1)
        rm = fmaxf(rm, __shfl_xor(rm, d));
      rmax[j] = rm;
    }
    bool need = (rmax[0] > mrun[0] + 8.f) | (rmax[1] > mrun[1] + 8.f) |
                (rmax[2] > mrun[2] + 8.f) | (rmax[3] > mrun[3] + 8.f);
    if (__any(need)) {
      #pragma unroll
      for (int j = 0; j < 4; ++j) {
        float mnew = fmaxf(mrun[j], rmax[j]);
        float cf = exp2f(mrun[j] - mnew);
        mrun[j] = mnew;
        lrun[j] *= cf;
        #pragma unroll
        for (int nf = 0; nf < 4; ++nf)
          oacc[nf][j] *= cf;
      }
    }
    #pragma unroll
    for (int j = 0; j < 4; ++j) {
      float psum = 0.f;
      #pragma unroll
      for (int nf = 0; nf < 4; ++nf) {
        float pv = exp2f(sacc[nf][j] - mrun[j]);
        sacc[nf][j] = pv;
        psum += pv;
      }
      #pragma unroll
      for (int d = 1; d < 16; d <<= 1)
        psum += __shfl_xor(psum, d);
      lrun[j] += psum;
    }

    // P -> LDS (per-wave, stride 64, XOR-swizzled rows)
    #pragma unroll
    for (int nf = 0; nf < 4; ++nf)
      #pragma unroll
      for (int j = 0; j < 4; ++j) {
        int prow = lg * 4 + j;
        Ps[w][prow * 64 + ((nf * 16 + lr) ^ ((prow & 7) << 3))] = f2bf(sacc[nf][j]);
      }

    // PV
    #pragma unroll
    for (int kx = 0; kx < 2; ++kx) {
      bf16x8 pf = *reinterpret_cast<const bf16x8*>(
          &Ps[w][lr * 64 + ((kx * 32 + lg * 8) ^ ((lr & 7) << 3))]);
      bf16x8 vf[4];
      #pragma unroll
      for (int nf = 0; nf < 4; ++nf)
        vf[nf] = *reinterpret_cast<const bf16x8*>(
            &Vs[cur][(nf * 16 + lr) * 64 + ((kx * 32 + lg * 8) ^ ((lr & 7) << 3))]);
      #pragma unroll
      for (int nf = 0; nf < 4; ++nf)
        oacc[nf] = __builtin_amdgcn_mfma_f32_16x16x32_bf16(pf, vf[nf], oacc[nf], 0, 0, 0);
    }
    // NO end-of-round barrier: next round's __syncthreads handles all hazards
  }

  writeO();                                    // phase B epilogue
}

// ---------------------------------------------------------------- GEMM2: out proj (single-buffer)
__global__ __launch_bounds__(256) void k_gemm_out(const unsigned short* __restrict__ A,
                                                  const unsigned short* __restrict__ Bt,
                                                  const float* __restrict__ bias,
                                                  float* __restrict__ Out) {
  __shared__ unsigned short As[128 * 64];
  __shared__ unsigned short Bs[128 * 64];
  const int K = 1024;
  int bid = blockIdx.x;
  int swz = (bid % 8) * 32 + bid / 8;       // XCD-contiguous
  int tm = swz / 8, tn = swz % 8;
  int m0 = tm * 128, n0 = tn * 128;
  int tid = threadIdx.x;
  int w = tid >> 6, l = tid & 63;
  int lr = l & 15, lg = l >> 4;
  int wm = (w >> 1) * 64, wn = (w & 1) * 64;
  int srow = l >> 3, scol = (l & 7) * 8;

  f32x4 acc[4][4];
  #pragma unroll
  for (int i = 0; i < 4; ++i)
    #pragma unroll
    for (int j = 0; j < 4; ++j)
      acc[i][j] = (f32x4){0.f, 0.f, 0.f, 0.f};

  for (int k0 = 0; k0 < K; k0 += 64) {
    #pragma unroll
    for (int c = 0; c < 4; ++c) {
      int chunk = w * 4 + c;
      int row = chunk * 8 + srow;
      async16(&A[(size_t)(m0 + row) * K + k0 + scol], &As[chunk * 512]);
      async16(&Bt[(size_t)(n0 + row) * K + k0 + scol], &Bs[chunk * 512]);
    }
    __syncthreads();
    #pragma unroll
    for (int kk = 0; kk < 64; kk += 32) {
      bf16x8 af[4], bfr[4];
      #pragma unroll
      for (int mf = 0; mf < 4; ++mf)
        af[mf] = *reinterpret_cast<const bf16x8*>(&As[(wm + mf * 16 + lr) * 64 + kk + lg * 8]);
      #pragma unroll
      for (int nf = 0; nf < 4; ++nf)
        bfr[nf] = *reinterpret_cast<const bf16x8*>(&Bs[(wn + nf * 16 + lr) * 64 + kk + lg * 8]);
      #pragma unroll
      for (int mf = 0; mf < 4; ++mf)
        #pragma unroll
        for (int nf = 0; nf < 4; ++nf)
          acc[mf][nf] = __builtin_amdgcn_mfma_f32_16x16x32_bf16(af[mf], bfr[nf], acc[mf][nf], 0, 0, 0);
    }
    __syncthreads();
  }

  #pragma unroll
  for (int mf = 0; mf < 4; ++mf)
    #pragma unroll
    for (int nf = 0; nf < 4; ++nf) {
      int n = n0 + wn + nf * 16 + lr;
      float bv = bias[n];
      #pragma unroll
      for (int j = 0; j < 4; ++j) {
        int m = m0 + wm + mf * 16 + lg * 4 + j;
        Out[(size_t)m * 1024 + n] = acc[mf][nf][j] + bv;
      }
    }
}

// ---------------------------------------------------------------- launch
extern "C" void kernel_launch(void* const* d_in, const int* in_sizes, int n_in,
                              void* d_out, int out_size, void* d_ws, size_t ws_size,
                              hipStream_t stream) {
  (void)in_sizes; (void)n_in; (void)out_size; (void)ws_size;
  const float* x      = (const float*)d_in[0];
  const float* w_qkv  = (const float*)d_in[2];
  const float* b_qkv  = (const float*)d_in[3];
  const float* w_proj = (const float*)d_in[4];
  const float* b_proj = (const float*)d_in[5];
  float* out = (float*)d_out;

  char* ws = (char*)d_ws;
  unsigned short* xb    = (unsigned short*)(ws);              //  8 MB [4096][1024]
  unsigned short* wqkvT = (unsigned short*)(ws + 8388608);    //  6 MB [3072][1024]
  unsigned short* wpT   = (unsigned short*)(ws + 14680064);   //  2 MB [1024][1024]
  unsigned short* Qg    = (unsigned short*)(ws + 16777216);   //  8 MB [32][2048][64]
  unsigned short* Kg    = (unsigned short*)(ws + 25165824);   //  8 MB [32][2048][64]
  unsigned short* Vt    = (unsigned short*)(ws + 33554432);   //  8 MB [32][64][2048]
  unsigned short* attnb = (unsigned short*)(ws + 41943040);   //  8 MB [4096][1024]

  k_cvt_bf16<<<dim3(2048), dim3(256), 0, stream>>>(x, xb, Bb * Ss * Dd);
  k_transpose_bf16<<<dim3(96, 32), dim3(32, 8), 0, stream>>>(w_qkv, wqkvT, 1024, 3072);
  k_transpose_bf16<<<dim3(32, 32), dim3(32, 8), 0, stream>>>(w_proj, wpT, 1024, 1024);
  k_gemm_qkv<<<dim3(32 * 24), dim3(256), 0, stream>>>(xb, wqkvT, b_qkv, Qg, Kg, Vt);
  k_attn<<<dim3(512), dim3(256), 0, stream>>>(Qg, Kg, Vt, attnb);
  k_gemm_out<<<dim3(32 * 8), dim3(256), 0, stream>>>(attnb, wpT, b_proj, out);
}